// Round 1
// baseline (1707.738 us; speedup 1.0000x reference)
//
#include <hip/hip_runtime.h>
#include <math.h>

// Problem constants
#define BB 4
#define CC 256
#define HH 64
#define WW 64
#define COUT 256
#define OFFC 216   // DG*3*KH*KW = 8*3*9
#define DGRP 8
#define CPG 32     // C / DG
#define KK 9

// ---------------- Kernel 0: weight transpose  w[oc][c*9+k] -> wT[c*9+k][oc]
__global__ __launch_bounds__(256) void transpose_w_kernel(const float* __restrict__ w,
                                                          float* __restrict__ wT, int OC) {
    int idx = blockIdx.x * 256 + threadIdx.x;
    int total = OC * (CC * KK);
    if (idx < total) {
        int oc = idx / (CC * KK);
        int ck = idx % (CC * KK);
        wT[ck * OC + oc] = w[idx];
    }
}

// ---------------- Kernel 1: offset conv (3x3, pad 1) on extra_feat -> om[B][216][64][64]
// grid: (B*H, 2) ; block 256. Each wave g handles 27 out-channels; half = blockIdx.y*108.
__global__ __launch_bounds__(256) void off_conv_kernel(const float* __restrict__ xf,
                                                       const float* __restrict__ owT,
                                                       const float* __restrict__ off_b,
                                                       float* __restrict__ om) {
    int by = blockIdx.x;
    int b = by >> 6;
    int y = by & 63;
    int tid = threadIdx.x;
    int lane = tid & 63;
    int g = __builtin_amdgcn_readfirstlane(tid >> 6);
    int oc0 = blockIdx.y * 108 + g * 27;

    float acc[27];
#pragma unroll
    for (int j = 0; j < 27; j++) acc[j] = 0.f;

    const float* xb = xf + (size_t)b * CC * HH * WW;
    for (int c = 0; c < CC; c++) {
        const float* xc = xb + c * (HH * WW);
#pragma unroll
        for (int ky = 0; ky < 3; ky++) {
            int iy = y + ky - 1;
            bool yok = ((unsigned)iy < (unsigned)HH);
#pragma unroll
            for (int kx = 0; kx < 3; kx++) {
                int ix = lane + kx - 1;
                float v = (yok && ((unsigned)ix < (unsigned)WW)) ? xc[iy * WW + ix] : 0.f;
                const float* wrow = owT + (size_t)(c * KK + ky * 3 + kx) * OFFC + oc0;
#pragma unroll
                for (int j = 0; j < 27; j++) acc[j] = fmaf(v, wrow[j], acc[j]);
            }
        }
    }
#pragma unroll
    for (int j = 0; j < 27; j++) {
        int oc = oc0 + j;
        om[(((size_t)b * OFFC + oc) * HH + y) * WW + lane] = acc[j] + off_b[oc];
    }
}

// ---------------- Kernel 2: fused deformable sampling + main conv
// grid: (B*H, 2) ; block 256.  Each block: one (b,y) row, 128 out-channels (blockIdx.y half).
// Per wave g: 32 out-channels. Loop dg(8) x chunk(2x16 channels): stage sampled val in LDS, GEMM.
__global__ __launch_bounds__(256) void dconv_kernel(const float* __restrict__ x,
                                                    const float* __restrict__ om,
                                                    const float* __restrict__ wT,
                                                    const float* __restrict__ bias,
                                                    float* __restrict__ out) {
    __shared__ float s_py[KK][WW];
    __shared__ float s_px[KK][WW];
    __shared__ float s_m[KK][WW];
    __shared__ float s_val[16 * KK][WW];   // 16 channels x 9 taps x 64 px

    int by = blockIdx.x;
    int b = by >> 6;
    int y = by & 63;
    int tid = threadIdx.x;
    int lane = tid & 63;
    int g = __builtin_amdgcn_readfirstlane(tid >> 6);
    int ocbase = blockIdx.y * 128 + g * 32;

    float acc[32];
#pragma unroll
    for (int j = 0; j < 32; j++) acc[j] = 0.f;

    const float* xb = x + (size_t)b * CC * HH * WW;
    const float* omb = om + (size_t)b * OFFC * HH * WW;

    for (int dg = 0; dg < DGRP; dg++) {
        __syncthreads();   // pos/val buffers free to overwrite
        // Phase A: positions + mask for this deform group, all 9 taps x 64 px
        for (int i = tid; i < KK * WW; i += 256) {
            int k = i / WW;
            int p = i % WW;
            int ky = k / 3, kx = k % 3;
            float dy = omb[((size_t)(dg * 18 + 2 * k) * HH + y) * WW + p];
            float dx = omb[((size_t)(dg * 18 + 2 * k + 1) * HH + y) * WW + p];
            float mv = omb[((size_t)(144 + dg * KK + k) * HH + y) * WW + p];
            mv = 1.f / (1.f + expf(-mv));
            s_py[k][p] = (float)(y - 1 + ky) + dy;
            s_px[k][p] = (float)(p - 1 + kx) + dx;
            s_m[k][p] = mv;
        }
        for (int ch = 0; ch < 2; ch++) {
            __syncthreads();  // pos ready / prev GEMM done with s_val
            // Phase B: bilinear sample 16 channels x 9 taps x 64 px
            for (int i = tid; i < 16 * KK * WW; i += 256) {
                int c = i / (KK * WW);
                int rem = i % (KK * WW);
                int k = rem / WW;
                int p = rem % WW;
                const float* xc = xb + (size_t)(dg * CPG + ch * 16 + c) * (HH * WW);
                float py = s_py[k][p];
                float px = s_px[k][p];
                float mv = s_m[k][p];
                float y0f = floorf(py), x0f = floorf(px);
                float fy = py - y0f, fx = px - x0f;
                int y0 = (int)y0f, x0 = (int)x0f;
                float v = 0.f;
                bool y0ok = ((unsigned)y0 < (unsigned)HH);
                bool y1ok = ((unsigned)(y0 + 1) < (unsigned)HH);
                bool x0ok = ((unsigned)x0 < (unsigned)WW);
                bool x1ok = ((unsigned)(x0 + 1) < (unsigned)WW);
                float w00 = (1.f - fy) * (1.f - fx);
                float w01 = (1.f - fy) * fx;
                float w10 = fy * (1.f - fx);
                float w11 = fy * fx;
                if (y0ok && x0ok) v = fmaf(w00, xc[y0 * WW + x0], v);
                if (y0ok && x1ok) v = fmaf(w01, xc[y0 * WW + x0 + 1], v);
                if (y1ok && x0ok) v = fmaf(w10, xc[(y0 + 1) * WW + x0], v);
                if (y1ok && x1ok) v = fmaf(w11, xc[(y0 + 1) * WW + x0 + 1], v);
                s_val[c * KK + k][p] = v * mv;
            }
            __syncthreads();
            // Phase C: GEMM — 16 channels x 9 taps, 32 out-channels per thread
            for (int cc = 0; cc < 16; cc++) {
                int cglob = dg * CPG + ch * 16 + cc;
#pragma unroll
                for (int k = 0; k < KK; k++) {
                    float v = s_val[cc * KK + k][lane];
                    const float* wrow = wT + (size_t)(cglob * KK + k) * COUT + ocbase;
#pragma unroll
                    for (int j = 0; j < 32; j++) acc[j] = fmaf(v, wrow[j], acc[j]);
                }
            }
        }
    }

#pragma unroll
    for (int j = 0; j < 32; j++) {
        int oc = ocbase + j;
        out[(((size_t)b * COUT + oc) * HH + y) * WW + lane] = acc[j] + bias[oc];
    }
}

extern "C" void kernel_launch(void* const* d_in, const int* in_sizes, int n_in,
                              void* d_out, int out_size, void* d_ws, size_t ws_size,
                              hipStream_t stream) {
    const float* x = (const float*)d_in[0];
    const float* extra_feat = (const float*)d_in[1];
    const float* weight = (const float*)d_in[2];
    const float* bias = (const float*)d_in[3];
    const float* off_w = (const float*)d_in[4];
    const float* off_b = (const float*)d_in[5];
    float* out = (float*)d_out;

    // workspace layout (floats)
    float* om = (float*)d_ws;                          // 4*216*64*64   = 3,538,944
    float* wT = om + (size_t)BB * OFFC * HH * WW;      // 2304*256      =   589,824
    float* owT = wT + (size_t)CC * KK * COUT;          // 2304*216      =   497,664

    // transpose weights
    transpose_w_kernel<<<(COUT * CC * KK + 255) / 256, 256, 0, stream>>>(weight, wT, COUT);
    transpose_w_kernel<<<(OFFC * CC * KK + 255) / 256, 256, 0, stream>>>(off_w, owT, OFFC);

    // offset conv on extra_feat
    off_conv_kernel<<<dim3(BB * HH, 2), 256, 0, stream>>>(extra_feat, owT, off_b, om);

    // fused deformable conv
    dconv_kernel<<<dim3(BB * HH, 2), 256, 0, stream>>>(x, om, wT, bias, out);
}

// Round 2
// 299.374 us; speedup vs baseline: 5.7044x; 5.7044x over previous
//
#include <hip/hip_runtime.h>
#include <math.h>

#define BB 4
#define CC 256
#define HH 64
#define WW 64
#define COUT 256
#define OFFC 216   // 8*27 real out channels of offset conv
#define MPAD 256   // padded M for offset conv
#define KTOT 2304  // 256*9
#define NCHUNK 72  // KTOT/32

typedef __attribute__((ext_vector_type(4))) float f32x4;
typedef __attribute__((ext_vector_type(8))) short s16x8;

__device__ __forceinline__ unsigned short f2bf(float f) {
    unsigned int u = __float_as_uint(f);
    unsigned int r = (u + 0x7fffu + ((u >> 16) & 1u)) >> 16;
    return (unsigned short)r;
}

// ---------- pack main weight: wpack[t][oc][kk], t=dg*9+tap, kk=cpg  (bf16)
__global__ __launch_bounds__(256) void pack_w_main(const float* __restrict__ w,
                                                   unsigned short* __restrict__ wp) {
    int idx = blockIdx.x * 256 + threadIdx.x;            // < 2304*256
    int t = idx >> 13;          // /8192
    int r = idx & 8191;
    int oc = r >> 5;
    int kk = r & 31;
    int dg = t / 9, tap = t % 9;
    int c = dg * 32 + kk;
    wp[idx] = f2bf(w[((size_t)oc * CC + c) * 9 + tap]);
}

// ---------- pack offset weight (padded to 256 oc): t = tap*8+cg, kk: c=cg*32+kk
__global__ __launch_bounds__(256) void pack_w_off(const float* __restrict__ w,
                                                  unsigned short* __restrict__ wp) {
    int idx = blockIdx.x * 256 + threadIdx.x;
    int t = idx >> 13;
    int r = idx & 8191;
    int oc = r >> 5;
    int kk = r & 31;
    int tap = t >> 3, cg = t & 7;
    int c = cg * 32 + kk;
    float v = (oc < OFFC) ? w[((size_t)oc * CC + c) * 9 + tap] : 0.f;
    wp[idx] = f2bf(v);
}

// ---------- offset conv via MFMA: out om[b][oc<216][y][x]
// block: one (b,y) row, M=256(pad), N=64. K chunk = (tap, 32 channels).
__global__ __launch_bounds__(256) void off_mfma(const float* __restrict__ xf,
                                                const unsigned short* __restrict__ wp,
                                                const float* __restrict__ off_b,
                                                float* __restrict__ om) {
    __shared__ unsigned short sA[256 * 40];
    __shared__ unsigned short sB[64 * 40];

    int blk = blockIdx.x;
    int b = blk >> 6, y = blk & 63;
    int tid = threadIdx.x;
    int lane = tid & 63;
    int wid = tid >> 6;
    int r16 = lane & 15, lg = lane >> 4;
    int px = tid & 63;
    int cq4 = tid >> 6;

    f32x4 acc[4][4];
#pragma unroll
    for (int mi = 0; mi < 4; mi++)
#pragma unroll
        for (int ni = 0; ni < 4; ni++) acc[mi][ni] = (f32x4)0.f;

    const float* xb = xf + (size_t)b * CC * HH * WW;

    for (int t = 0; t < NCHUNK; t++) {
        int tap = t >> 3, cg = t & 7;
        int ky = tap / 3, kx = tap % 3;
        __syncthreads();
        // stage A: copy 256x32 bf16 from wpack chunk
        {
            const s16x8* src = (const s16x8*)(wp + (size_t)t * 8192);
#pragma unroll
            for (int s = 0; s < 4; s++) {
                int i = tid + 256 * s;
                int oc = i >> 2;
                int kk0 = (i & 3) * 8;
                *(s16x8*)&sA[oc * 40 + kk0] = src[i];
            }
        }
        // stage B: im2col 32 channels x 64 px
        {
            int iy = y + ky - 1;
            int ix = px + kx - 1;
            bool ok = ((unsigned)iy < (unsigned)HH) && ((unsigned)ix < (unsigned)WW);
            const float* base = xb + ((size_t)(cg * 32) * HH + (ok ? iy : 0)) * WW + (ok ? ix : 0);
#pragma unroll
            for (int j = 0; j < 4; j++) {
                int cq = cq4 * 4 + j;
                float v0 = ok ? base[(size_t)(cq * 2) * HH * WW] : 0.f;
                float v1 = ok ? base[(size_t)(cq * 2 + 1) * HH * WW] : 0.f;
                unsigned int pk = ((unsigned int)f2bf(v1) << 16) | f2bf(v0);
                *(unsigned int*)&sB[px * 40 + cq * 2] = pk;
            }
        }
        __syncthreads();
        // MFMA: wave computes 64(M) x 64(N)
        s16x8 af[4], bfv[4];
#pragma unroll
        for (int mi = 0; mi < 4; mi++)
            af[mi] = *(const s16x8*)&sA[(wid * 64 + mi * 16 + r16) * 40 + lg * 8];
#pragma unroll
        for (int ni = 0; ni < 4; ni++)
            bfv[ni] = *(const s16x8*)&sB[(ni * 16 + r16) * 40 + lg * 8];
#pragma unroll
        for (int mi = 0; mi < 4; mi++)
#pragma unroll
            for (int ni = 0; ni < 4; ni++)
                acc[mi][ni] = __builtin_amdgcn_mfma_f32_16x16x32_bf16(af[mi], bfv[ni], acc[mi][ni], 0, 0, 0);
    }

#pragma unroll
    for (int mi = 0; mi < 4; mi++) {
#pragma unroll
        for (int ni = 0; ni < 4; ni++) {
#pragma unroll
            for (int j = 0; j < 4; j++) {
                int oc = wid * 64 + mi * 16 + lg * 4 + j;
                int pxo = ni * 16 + r16;
                if (oc < OFFC)
                    om[(((size_t)b * OFFC + oc) * HH + y) * WW + pxo] = acc[mi][ni][j] + off_b[oc];
            }
        }
    }
}

// ---------- fused deformable sampling + main conv via MFMA
// block: one (b,y) row, M=256, N=64. K chunk = (dg, tap) -> 32 channels of dg.
__global__ __launch_bounds__(256) void dconv_mfma(const float* __restrict__ x,
                                                  const float* __restrict__ om,
                                                  const unsigned short* __restrict__ wp,
                                                  const float* __restrict__ bias,
                                                  float* __restrict__ out) {
    __shared__ unsigned short sA[256 * 40];
    __shared__ unsigned short sB[64 * 40];

    int blk = blockIdx.x;
    int b = blk >> 6, y = blk & 63;
    int tid = threadIdx.x;
    int lane = tid & 63;
    int wid = tid >> 6;
    int r16 = lane & 15, lg = lane >> 4;
    int px = tid & 63;
    int cq4 = tid >> 6;

    f32x4 acc[4][4];
#pragma unroll
    for (int mi = 0; mi < 4; mi++)
#pragma unroll
        for (int ni = 0; ni < 4; ni++) acc[mi][ni] = (f32x4)0.f;

    const float* xb = x + (size_t)b * CC * HH * WW;
    const float* omb = om + (size_t)b * OFFC * HH * WW;

    for (int t = 0; t < NCHUNK; t++) {
        int dg = t / 9, tap = t % 9;
        int ky = tap / 3, kx = tap % 3;
        __syncthreads();
        // stage A
        {
            const s16x8* src = (const s16x8*)(wp + (size_t)t * 8192);
#pragma unroll
            for (int s = 0; s < 4; s++) {
                int i = tid + 256 * s;
                int oc = i >> 2;
                int kk0 = (i & 3) * 8;
                *(s16x8*)&sA[oc * 40 + kk0] = src[i];
            }
        }
        // stage B: bilinear sample 32 channels (this dg) x 64 px
        {
            float dy_ = omb[((size_t)(dg * 18 + 2 * tap) * HH + y) * WW + px];
            float dx_ = omb[((size_t)(dg * 18 + 2 * tap + 1) * HH + y) * WW + px];
            float mv = omb[((size_t)(144 + dg * 9 + tap) * HH + y) * WW + px];
            mv = 1.f / (1.f + expf(-mv));
            float py = (float)(y + ky - 1) + dy_;
            float pxf = (float)(px + kx - 1) + dx_;
            float y0f = floorf(py), x0f = floorf(pxf);
            float fy = py - y0f, fx = pxf - x0f;
            int y0 = (int)y0f, x0 = (int)x0f;
            bool y0k = (unsigned)y0 < (unsigned)HH;
            bool y1k = (unsigned)(y0 + 1) < (unsigned)HH;
            bool x0k = (unsigned)x0 < (unsigned)WW;
            bool x1k = (unsigned)(x0 + 1) < (unsigned)WW;
            float w00 = (1.f - fy) * (1.f - fx) * mv;
            float w01 = (1.f - fy) * fx * mv;
            float w10 = fy * (1.f - fx) * mv;
            float w11 = fy * fx * mv;
            w00 = (y0k && x0k) ? w00 : 0.f;
            w01 = (y0k && x1k) ? w01 : 0.f;
            w10 = (y1k && x0k) ? w10 : 0.f;
            w11 = (y1k && x1k) ? w11 : 0.f;
            int yc0 = min(max(y0, 0), HH - 1), yc1 = min(max(y0 + 1, 0), HH - 1);
            int xc0 = min(max(x0, 0), WW - 1), xc1 = min(max(x0 + 1, 0), WW - 1);
            int i00 = yc0 * WW + xc0, i01 = yc0 * WW + xc1;
            int i10 = yc1 * WW + xc0, i11 = yc1 * WW + xc1;
#pragma unroll
            for (int j = 0; j < 4; j++) {
                int cq = cq4 * 4 + j;
                const float* xc0p = xb + (size_t)(dg * 32 + cq * 2) * (HH * WW);
                const float* xc1p = xc0p + HH * WW;
                float v0 = w00 * xc0p[i00] + w01 * xc0p[i01] + w10 * xc0p[i10] + w11 * xc0p[i11];
                float v1 = w00 * xc1p[i00] + w01 * xc1p[i01] + w10 * xc1p[i10] + w11 * xc1p[i11];
                unsigned int pk = ((unsigned int)f2bf(v1) << 16) | f2bf(v0);
                *(unsigned int*)&sB[px * 40 + cq * 2] = pk;
            }
        }
        __syncthreads();
        // MFMA
        s16x8 af[4], bfv[4];
#pragma unroll
        for (int mi = 0; mi < 4; mi++)
            af[mi] = *(const s16x8*)&sA[(wid * 64 + mi * 16 + r16) * 40 + lg * 8];
#pragma unroll
        for (int ni = 0; ni < 4; ni++)
            bfv[ni] = *(const s16x8*)&sB[(ni * 16 + r16) * 40 + lg * 8];
#pragma unroll
        for (int mi = 0; mi < 4; mi++)
#pragma unroll
            for (int ni = 0; ni < 4; ni++)
                acc[mi][ni] = __builtin_amdgcn_mfma_f32_16x16x32_bf16(af[mi], bfv[ni], acc[mi][ni], 0, 0, 0);
    }

#pragma unroll
    for (int mi = 0; mi < 4; mi++) {
#pragma unroll
        for (int ni = 0; ni < 4; ni++) {
#pragma unroll
            for (int j = 0; j < 4; j++) {
                int oc = wid * 64 + mi * 16 + lg * 4 + j;
                int pxo = ni * 16 + r16;
                out[(((size_t)b * COUT + oc) * HH + y) * WW + pxo] = acc[mi][ni][j] + bias[oc];
            }
        }
    }
}

extern "C" void kernel_launch(void* const* d_in, const int* in_sizes, int n_in,
                              void* d_out, int out_size, void* d_ws, size_t ws_size,
                              hipStream_t stream) {
    const float* x = (const float*)d_in[0];
    const float* extra_feat = (const float*)d_in[1];
    const float* weight = (const float*)d_in[2];
    const float* bias = (const float*)d_in[3];
    const float* off_w = (const float*)d_in[4];
    const float* off_b = (const float*)d_in[5];
    float* out = (float*)d_out;

    float* om = (float*)d_ws;                                       // 4*216*64*64 f32
    unsigned short* wpm = (unsigned short*)(om + (size_t)BB * OFFC * HH * WW);  // 2304*256 bf16
    unsigned short* wpo = wpm + (size_t)KTOT * COUT;                // 2304*256 bf16 (padded)

    pack_w_main<<<(KTOT * COUT) / 256, 256, 0, stream>>>(weight, wpm);
    pack_w_off<<<(KTOT * MPAD) / 256, 256, 0, stream>>>(off_w, wpo);

    off_mfma<<<BB * HH, 256, 0, stream>>>(extra_feat, wpo, off_b, om);
    dconv_mfma<<<BB * HH, 256, 0, stream>>>(x, om, wpm, bias, out);
}

// Round 3
// 192.565 us; speedup vs baseline: 8.8684x; 1.5547x over previous
//
#include <hip/hip_runtime.h>
#include <math.h>

#define BB 4
#define CC 256
#define HH 64
#define WW 64
#define PH 68         // padded H (+2 ring each side)
#define PW 68
#define COUT 256
#define OFFC 216      // real offset-conv out channels
#define KTOT 2304
#define NCHUNK 72     // KTOT/32

typedef __attribute__((ext_vector_type(4))) float f32x4;
typedef __attribute__((ext_vector_type(8))) short s16x8;
typedef __attribute__((ext_vector_type(8))) unsigned short u16x8;

__device__ __forceinline__ unsigned short f2bf(float f) {
    unsigned int u = __float_as_uint(f);
    return (unsigned short)((u + 0x7fffu + ((u >> 16) & 1u)) >> 16);
}
__device__ __forceinline__ float bf2f(unsigned short h) {
    return __uint_as_float(((unsigned int)h) << 16);
}

// ---------- pack main weight: wp[t][oc][kk], t=dg*9+tap, c=dg*32+kk
__global__ __launch_bounds__(256) void pack_w_main(const float* __restrict__ w,
                                                   unsigned short* __restrict__ wp) {
    int idx = blockIdx.x * 256 + threadIdx.x;
    int t = idx >> 13;
    int r = idx & 8191;
    int oc = r >> 5;
    int kk = r & 31;
    int dg = t / 9, tap = t % 9;
    int c = dg * 32 + kk;
    wp[idx] = f2bf(w[((size_t)oc * CC + c) * 9 + tap]);
}

// ---------- pack offset weight (pad 216->256 oc): t = tap*8+cg, c=cg*32+kk
__global__ __launch_bounds__(256) void pack_w_off(const float* __restrict__ w,
                                                  unsigned short* __restrict__ wp) {
    int idx = blockIdx.x * 256 + threadIdx.x;
    int t = idx >> 13;
    int r = idx & 8191;
    int oc = r >> 5;
    int kk = r & 31;
    int tap = t >> 3, cg = t & 7;
    int c = cg * 32 + kk;
    float v = (oc < OFFC) ? w[((size_t)oc * CC + c) * 9 + tap] : 0.f;
    wp[idx] = f2bf(v);
}

// ---------- NCHW f32 -> padded NHWC bf16 with zero ring of 2
__global__ __launch_bounds__(256) void pad_tr(const float* __restrict__ src,
                                              unsigned short* __restrict__ dst) {
    int idx = blockIdx.x * 256 + threadIdx.x;   // b*PH*PW*32
    int c8 = idx & 31;
    int r = idx >> 5;
    int xp = r % PW; r /= PW;
    int yp = r % PH;
    int b = r / PH;
    int y = yp - 2, x = xp - 2;
    u16x8 o = (u16x8)0;
    if (((unsigned)y < (unsigned)HH) && ((unsigned)x < (unsigned)WW)) {
        const float* s = src + (((size_t)b * CC + c8 * 8) * HH + y) * WW + x;
#pragma unroll
        for (int j = 0; j < 8; j++) o[j] = f2bf(s[(size_t)j * HH * WW]);
    }
    *(u16x8*)&dst[(((size_t)b * PH + yp) * PW + xp) * CC + c8 * 8] = o;
}

// ---------- offset conv: A(weights) from L2->regs prefetched, B(im2col) dbuf LDS
__global__ __launch_bounds__(256) void off_mfma(const unsigned short* __restrict__ eT,
                                                const unsigned short* __restrict__ wp,
                                                const float* __restrict__ off_b,
                                                float* __restrict__ om) {
    __shared__ unsigned short sB[2][64][40];
    int blk = blockIdx.x;
    int b = blk >> 6, y = blk & 63;
    int tid = threadIdx.x;
    int lane = tid & 63, wid = tid >> 6;
    int r16 = lane & 15, lg = lane >> 4;
    int px = tid & 63, cq4 = tid >> 6;

    const unsigned short* eb = eT + (size_t)b * PH * PW * CC;

    f32x4 acc[4][4];
#pragma unroll
    for (int mi = 0; mi < 4; mi++)
#pragma unroll
        for (int ni = 0; ni < 4; ni++) acc[mi][ni] = (f32x4)0.f;

    s16x8 afA[4], afB[4];

#define OFF_BLOAD(T, NV)                                                          \
    {                                                                             \
        int tap_ = (T) >> 3, cg_ = (T) & 7;                                       \
        int ky_ = tap_ / 3, kx_ = tap_ % 3;                                       \
        int iy_ = y + ky_ + 1, ix_ = px + kx_ + 1;                                \
        NV = *(const s16x8*)&eb[((size_t)iy_ * PW + ix_) * CC + cg_ * 32 + cq4 * 8]; \
    }
#define OFF_ALOAD(T, AF)                                                          \
    {                                                                             \
        const unsigned short* wt_ = wp + (size_t)(T) * 8192 +                     \
                                    (size_t)(wid * 64 + r16) * 32 + lg * 8;       \
        _Pragma("unroll") for (int mi = 0; mi < 4; mi++)                          \
            AF[mi] = *(const s16x8*)&wt_[mi * 512];                               \
    }

    {
        s16x8 v;
        OFF_BLOAD(0, v)
        *(s16x8*)&sB[0][px][cq4 * 8] = v;
        OFF_ALOAD(0, afA)
    }

#define OFF_ITER(T, AFC, AFN, BUF)                                                \
    {                                                                             \
        __syncthreads();                                                          \
        s16x8 bfv[4];                                                             \
        _Pragma("unroll") for (int ni = 0; ni < 4; ni++)                          \
            bfv[ni] = *(const s16x8*)&sB[BUF][ni * 16 + r16][lg * 8];             \
        s16x8 nv = (s16x8)0;                                                      \
        if ((T) + 1 < NCHUNK) {                                                   \
            OFF_BLOAD((T) + 1, nv)                                                \
            OFF_ALOAD((T) + 1, AFN)                                               \
        }                                                                         \
        _Pragma("unroll") for (int mi = 0; mi < 4; mi++)                          \
        _Pragma("unroll") for (int ni = 0; ni < 4; ni++)                          \
            acc[mi][ni] = __builtin_amdgcn_mfma_f32_16x16x32_bf16(                \
                AFC[mi], bfv[ni], acc[mi][ni], 0, 0, 0);                          \
        if ((T) + 1 < NCHUNK) *(s16x8*)&sB[(BUF) ^ 1][px][cq4 * 8] = nv;          \
    }

    for (int t = 0; t < NCHUNK; t += 2) {
        OFF_ITER(t, afA, afB, 0)
        OFF_ITER(t + 1, afB, afA, 1)
    }

#pragma unroll
    for (int mi = 0; mi < 4; mi++) {
#pragma unroll
        for (int ni = 0; ni < 4; ni++) {
#pragma unroll
            for (int j = 0; j < 4; j++) {
                int oc = wid * 64 + mi * 16 + lg * 4 + j;
                int pxo = ni * 16 + r16;
                if (oc < OFFC)
                    om[(((size_t)b * OFFC + oc) * HH + y) * WW + pxo] = acc[mi][ni][j] + off_b[oc];
            }
        }
    }
}

// ---------- fused deformable sampling + main conv
__global__ __launch_bounds__(256) void dconv_mfma(const unsigned short* __restrict__ xT,
                                                  const float* __restrict__ om,
                                                  const unsigned short* __restrict__ wp,
                                                  const float* __restrict__ bias,
                                                  float* __restrict__ out) {
    __shared__ unsigned short sB[2][64][40];
    int blk = blockIdx.x;
    int b = blk >> 6, y = blk & 63;
    int tid = threadIdx.x;
    int lane = tid & 63, wid = tid >> 6;
    int r16 = lane & 15, lg = lane >> 4;
    int px = tid & 63, cq4 = tid >> 6;

    const unsigned short* xb = xT + (size_t)b * PH * PW * CC;
    const float* omb = om + (size_t)b * OFFC * HH * WW;

    f32x4 acc[4][4];
#pragma unroll
    for (int mi = 0; mi < 4; mi++)
#pragma unroll
        for (int ni = 0; ni < 4; ni++) acc[mi][ni] = (f32x4)0.f;

    s16x8 afA[4], afB[4];

    // issue part: positions + 4 corner dwordx4 gathers (8 channels each)
#define D_ISSUE(T, C00, C01, C10, C11, W4)                                        \
    {                                                                             \
        int dg_ = (T) / 9, tap_ = (T) % 9;                                        \
        int ky_ = tap_ / 3, kx_ = tap_ % 3;                                       \
        float dy_ = omb[((size_t)(dg_ * 18 + 2 * tap_) * HH + y) * WW + px];      \
        float dx_ = omb[((size_t)(dg_ * 18 + 2 * tap_ + 1) * HH + y) * WW + px];  \
        float mr_ = omb[((size_t)(144 + dg_ * 9 + tap_) * HH + y) * WW + px];     \
        float mv_ = 1.f / (1.f + __expf(-mr_));                                   \
        float py_ = (float)(y + ky_ - 1) + dy_;                                   \
        float pxx_ = (float)(px + kx_ - 1) + dx_;                                 \
        float y0f_ = floorf(py_), x0f_ = floorf(pxx_);                            \
        float fy_ = py_ - y0f_, fx_ = pxx_ - x0f_;                                \
        int y0_ = (int)y0f_, x0_ = (int)x0f_;                                     \
        int yp0_ = min(max(y0_ + 2, 0), PH - 1);                                  \
        int yp1_ = min(max(y0_ + 3, 0), PH - 1);                                  \
        int xp0_ = min(max(x0_ + 2, 0), PW - 1);                                  \
        int xp1_ = min(max(x0_ + 3, 0), PW - 1);                                  \
        int cb_ = dg_ * 32 + cq4 * 8;                                             \
        const unsigned short* r0_ = xb + (size_t)yp0_ * PW * CC + cb_;            \
        const unsigned short* r1_ = xb + (size_t)yp1_ * PW * CC + cb_;            \
        C00 = *(const s16x8*)&r0_[(size_t)xp0_ * CC];                             \
        C01 = *(const s16x8*)&r0_[(size_t)xp1_ * CC];                             \
        C10 = *(const s16x8*)&r1_[(size_t)xp0_ * CC];                             \
        C11 = *(const s16x8*)&r1_[(size_t)xp1_ * CC];                             \
        W4[0] = (1.f - fy_) * (1.f - fx_) * mv_;                                  \
        W4[1] = (1.f - fy_) * fx_ * mv_;                                          \
        W4[2] = fy_ * (1.f - fx_) * mv_;                                          \
        W4[3] = fy_ * fx_ * mv_;                                                  \
    }
    // finish part: bilinear combine + bf16 pack
#define D_FINISH(C00, C01, C10, C11, W4, NV)                                      \
    {                                                                             \
        _Pragma("unroll") for (int j = 0; j < 8; j++) {                           \
            float v_ = W4[0] * bf2f((unsigned short)C00[j]) +                     \
                       W4[1] * bf2f((unsigned short)C01[j]) +                     \
                       W4[2] * bf2f((unsigned short)C10[j]) +                     \
                       W4[3] * bf2f((unsigned short)C11[j]);                      \
            NV[j] = (short)f2bf(v_);                                              \
        }                                                                         \
    }
#define D_ALOAD(T, AF)                                                            \
    {                                                                             \
        const unsigned short* wt_ = wp + (size_t)(T) * 8192 +                     \
                                    (size_t)(wid * 64 + r16) * 32 + lg * 8;       \
        _Pragma("unroll") for (int mi = 0; mi < 4; mi++)                          \
            AF[mi] = *(const s16x8*)&wt_[mi * 512];                               \
    }

    {
        s16x8 c00, c01, c10, c11, nv;
        float w4[4];
        D_ISSUE(0, c00, c01, c10, c11, w4)
        D_FINISH(c00, c01, c10, c11, w4, nv)
        *(s16x8*)&sB[0][px][cq4 * 8] = nv;
        D_ALOAD(0, afA)
    }

#define D_ITER(T, AFC, AFN, BUF)                                                  \
    {                                                                             \
        __syncthreads();                                                          \
        s16x8 bfv[4];                                                             \
        _Pragma("unroll") for (int ni = 0; ni < 4; ni++)                          \
            bfv[ni] = *(const s16x8*)&sB[BUF][ni * 16 + r16][lg * 8];             \
        s16x8 c00, c01, c10, c11;                                                 \
        float w4[4];                                                              \
        if ((T) + 1 < NCHUNK) {                                                   \
            D_ISSUE((T) + 1, c00, c01, c10, c11, w4)                              \
            D_ALOAD((T) + 1, AFN)                                                 \
        }                                                                         \
        _Pragma("unroll") for (int mi = 0; mi < 4; mi++)                          \
        _Pragma("unroll") for (int ni = 0; ni < 4; ni++)                          \
            acc[mi][ni] = __builtin_amdgcn_mfma_f32_16x16x32_bf16(                \
                AFC[mi], bfv[ni], acc[mi][ni], 0, 0, 0);                          \
        if ((T) + 1 < NCHUNK) {                                                   \
            s16x8 nv;                                                             \
            D_FINISH(c00, c01, c10, c11, w4, nv)                                  \
            *(s16x8*)&sB[(BUF) ^ 1][px][cq4 * 8] = nv;                            \
        }                                                                         \
    }

    for (int t = 0; t < NCHUNK; t += 2) {
        D_ITER(t, afA, afB, 0)
        D_ITER(t + 1, afB, afA, 1)
    }

#pragma unroll
    for (int mi = 0; mi < 4; mi++) {
#pragma unroll
        for (int ni = 0; ni < 4; ni++) {
#pragma unroll
            for (int j = 0; j < 4; j++) {
                int oc = wid * 64 + mi * 16 + lg * 4 + j;
                int pxo = ni * 16 + r16;
                out[(((size_t)b * COUT + oc) * HH + y) * WW + pxo] = acc[mi][ni][j] + bias[oc];
            }
        }
    }
}

extern "C" void kernel_launch(void* const* d_in, const int* in_sizes, int n_in,
                              void* d_out, int out_size, void* d_ws, size_t ws_size,
                              hipStream_t stream) {
    const float* x = (const float*)d_in[0];
    const float* extra_feat = (const float*)d_in[1];
    const float* weight = (const float*)d_in[2];
    const float* bias = (const float*)d_in[3];
    const float* off_w = (const float*)d_in[4];
    const float* off_b = (const float*)d_in[5];
    float* out = (float*)d_out;

    // workspace layout
    float* om = (float*)d_ws;                                   // 4*216*64*64 f32
    unsigned short* wpm = (unsigned short*)(om + (size_t)BB * OFFC * HH * WW);
    unsigned short* wpo = wpm + (size_t)KTOT * COUT;            // 2304*256
    unsigned short* xT = wpo + (size_t)KTOT * COUT;             // 4*68*68*256
    unsigned short* eT = xT + (size_t)BB * PH * PW * CC;        // 4*68*68*256

    pack_w_main<<<(KTOT * COUT) / 256, 256, 0, stream>>>(weight, wpm);
    pack_w_off<<<(KTOT * COUT) / 256, 256, 0, stream>>>(off_w, wpo);
    pad_tr<<<(BB * PH * PW * 32) / 256, 256, 0, stream>>>(x, xT);
    pad_tr<<<(BB * PH * PW * 32) / 256, 256, 0, stream>>>(extra_feat, eT);

    off_mfma<<<BB * HH, 256, 0, stream>>>(eT, wpo, off_b, om);
    dconv_mfma<<<BB * HH, 256, 0, stream>>>(xT, om, wpm, bias, out);
}